// Round 2
// baseline (241.979 us; speedup 1.0000x reference)
//
#include <hip/hip_runtime.h>
#include <math.h>

#define B_    4
#define C_    19
#define H_    320
#define W_    320
#define HW_   (H_*W_)
#define CHW_  (C_*HW_)
#define NPIX_ (B_*HW_)
#define NEPS_ 256
#define BIGI_ (1<<20)
#define INF_  0x3fffffff
#define IGN_  255

// ---------------- reduction helper (256-thread blocks = 4 waves) -------------
__device__ __forceinline__ void block_reduce_add_256(float v, float* out) {
  #pragma unroll
  for (int o = 32; o > 0; o >>= 1) v += __shfl_down(v, o);
  __shared__ float sh[4];
  int lane = threadIdx.x & 63, wid = threadIdx.x >> 6;
  if (lane == 0) sh[wid] = v;
  __syncthreads();
  if (threadIdx.x == 0) atomicAdd(out, sh[0] + sh[1] + sh[2] + sh[3]);
}

// ---------------- row-wise 1D seed distance (Hillis-Steele min scans) --------
// Block 0 additionally initializes eps table / hist / out (runs before k_stats
// and k_klmap in stream order).
__global__ __launch_bounds__(W_) void k_rowdt(const int* __restrict__ tgt, int* __restrict__ R,
                                              float* eps_tab, int* hist, float* out) {
  int b = blockIdx.x / H_, i = blockIdx.x % H_, j = threadIdx.x;
  const int* t = tgt + b * HW_;
  int tij = t[i*W_ + j];
  bool bnd = (tij == IGN_);
  if (i < H_-1) bnd |= (t[(i+1)*W_ + j] != tij);
  if (j < W_-1) bnd |= (t[i*W_ + j + 1] != tij);
  int s = bnd ? 0 : BIGI_;
  __shared__ int a[W_], c[W_];
  a[j] = s - j; c[j] = s + j;
  for (int ofs = 1; ofs < W_; ofs <<= 1) {
    __syncthreads();
    int av = (j >= ofs)      ? a[j-ofs] : INF_;
    int cv = (j + ofs < W_)  ? c[j+ofs] : INF_;
    __syncthreads();
    a[j] = min(a[j], av); c[j] = min(c[j], cv);
  }
  int Rv = min(a[j] + j, c[j] - j);
  R[(b*H_ + i)*W_ + j] = Rv;
  if (blockIdx.x == 0) {
    if (j < 257) hist[j] = 0;
    if (j == 0) {
      float e = 1e-5f;
      for (int k = 0; k < NEPS_; ++k) { eps_tab[k] = e; e *= 1.2f; }
      out[0] = 0.f;
    }
  }
}

// ---------------- column combine: dist = min_i max(|i-i0|, R_i) -------------
__global__ __launch_bounds__(H_) void k_coldt(const int* __restrict__ R, int* __restrict__ dist) {
  int b = blockIdx.x / W_, j = blockIdx.x % W_, tid = threadIdx.x;
  __shared__ int lev[9][H_];
  lev[0][tid] = R[(b*H_ + tid)*W_ + j];
  for (int l = 1; l <= 8; ++l) {
    int half = 1 << (l-1);
    __syncthreads();
    int other = (tid + half < H_) ? lev[l-1][tid + half] : INF_;
    lev[l][tid] = min(lev[l-1][tid], other);
  }
  __syncthreads();
  int i0 = tid;
  auto feas = [&](int dd) -> bool {
    int lo = max(0, i0 - dd), hi = min(H_-1, i0 + dd);
    int len = hi - lo + 1;
    int l = 31 - __clz(len);
    int m = min(lev[l][lo], lev[l][hi - (1 << l) + 1]);
    return m <= dd;
  };
  int d;
  if (!feas(512)) d = B_ + 1 + H_ + W_;          // 645: no seed in image
  else {
    int lo = 0, hi = 512;
    while (lo < hi) { int mid = (lo + hi) >> 1; if (feas(mid)) hi = mid; else lo = mid + 1; }
    d = lo;
  }
  dist[(b*H_ + i0)*W_ + j] = d;
}

// ---------------- per-pixel softmax stats + target loss ---------------------
__global__ __launch_bounds__(256) void k_stats(const float* __restrict__ sl, const int* __restrict__ tgt,
                                               float* __restrict__ logZ, float* __restrict__ S,
                                               float* __restrict__ out) {
  int idx = blockIdx.x * 256 + threadIdx.x;
  int b = idx / HW_; int pix = idx - b * HW_;
  const float* base = sl + (size_t)b * CHW_ + pix;
  float x[C_]; float m = -1e30f;
  #pragma unroll
  for (int c = 0; c < C_; ++c) { x[c] = base[c*HW_]; m = fmaxf(m, x[c]); }
  float se = 0.f, E = 0.f;
  #pragma unroll
  for (int c = 0; c < C_; ++c) { float e = expf(x[c] - m); se += e; E += e * x[c]; }
  float lz = m + logf(se);
  logZ[idx] = lz;
  S[idx] = E / se - lz;
  int t = tgt[idx];
  float nll = (t != IGN_) ? (lz - base[t*HW_]) : 0.f;
  block_reduce_add_256(nll, out);
}

// ---------------- kl_map (tb+lr KL) + histogram over eps table --------------
__global__ __launch_bounds__(256) void k_klmap(const float* __restrict__ sl, const float* __restrict__ logZ,
                                               const float* __restrict__ S, float* __restrict__ kl_map,
                                               const float* __restrict__ eps_tab, int* __restrict__ hist) {
  __shared__ int sh[257];
  __shared__ float et[NEPS_];
  for (int e = threadIdx.x; e < 257; e += 256) sh[e] = 0;
  for (int e = threadIdx.x; e < NEPS_; e += 256) et[e] = eps_tab[e];
  __syncthreads();
  int idx = blockIdx.x * 256 + threadIdx.x;
  int b = idx / HW_; int pix = idx - b * HW_;
  int i = pix / W_, j = pix - i * W_;
  const float* base = sl + (size_t)b * CHW_ + pix;
  float lz = logZ[idx], Sv = S[idx];
  float p[C_];
  #pragma unroll
  for (int c = 0; c < C_; ++c) p[c] = expf(base[c*HW_] - lz);
  float kl = 0.f;
  if (i < H_-1) {
    const float* bd = base + W_;
    float dot = 0.f;
    #pragma unroll
    for (int c = 0; c < C_; ++c) dot += p[c] * bd[c*HW_];
    kl += Sv - (dot - logZ[idx + W_]);
  }
  if (j < W_-1) {
    const float* br = base + 1;
    float dot = 0.f;
    #pragma unroll
    for (int c = 0; c < C_; ++c) dot += p[c] * br[c*HW_];
    kl += Sv - (dot - logZ[idx + 1]);
  }
  kl_map[idx] = kl;
  // g = #{k : e_k < kl}  (lower_bound; identical float compare as reference)
  int lo = 0, hi = NEPS_;
  while (lo < hi) { int mid = (lo + hi) >> 1; if (et[mid] < kl) lo = mid + 1; else hi = mid; }
  atomicAdd(&sh[lo], 1);
  __syncthreads();
  for (int e = threadIdx.x; e < 257; e += 256)
    if (sh[e]) atomicAdd(&hist[e], sh[e]);
}

// ---------------- eps selection: first k with count(>e_k) <= 5120 -----------
__global__ __launch_bounds__(256) void k_eps(const int* __restrict__ hist, const float* __restrict__ eps_tab,
                                             float* __restrict__ eps_sel) {
  __shared__ int h[257];
  __shared__ int bestk;
  int t = threadIdx.x;
  h[t] = hist[t];
  if (t == 0) { h[256] = hist[256]; bestk = NEPS_ - 1; }
  __syncthreads();
  int cnt = 0;
  for (int m = t + 1; m <= 256; ++m) cnt += h[m];
  if (cnt <= 5120) atomicMin(&bestk, t);
  __syncthreads();
  if (t == 0) eps_sel[0] = eps_tab[bestk];
}

// ---------------- final: tiled, all logits staged in LDS --------------------
// 16x16 tile + 1-px halo. xs holds the full 19-channel 18x18 logit tile so the
// 8-neighbor KL dot products read LDS, not scattered HBM (R1: 66MB fetch here).
__global__ __launch_bounds__(256) void k_final(const float* __restrict__ sl, const int* __restrict__ dist,
                                               const float* __restrict__ kl_map, const float* __restrict__ logZ,
                                               const float* __restrict__ S, const float* __restrict__ eps_sel,
                                               float* __restrict__ out) {
  const int nx[9] = {1,-1,0,0,-1,1,-1,1,0};
  const int ny[9] = {0,0,-1,1,1,1,-1,-1,0};
  int b = blockIdx.z;
  int i0 = blockIdx.y * 16, j0 = blockIdx.x * 16;
  int tid = threadIdx.x; int li = tid >> 4, lj = tid & 15;
  __shared__ float xs[C_][18][18];   // 24624 B
  __shared__ float lzs[18][18];
  __shared__ float Ss[18][18];
  __shared__ float kls[18][18];
  __shared__ int   dss[18][18];
  float eps = eps_sel[0];
  for (int e = tid; e < 18*18; e += 256) {
    int r = e / 18, cc = e - r * 18;
    int gi = i0 - 1 + r, gj = j0 - 1 + cc;
    bool in = (gi >= 0 && gi < H_ && gj >= 0 && gj < W_);
    int ci = min(max(gi, 0), H_-1), cj = min(max(gj, 0), W_-1);
    int gidx = (b*H_ + ci)*W_ + cj;
    lzs[r][cc] = logZ[gidx];
    Ss[r][cc]  = S[gidx];
    kls[r][cc] = in ? kl_map[gidx] : -1e30f;
    dss[r][cc] = in ? dist[gidx] : 100000;
  }
  #pragma unroll 1
  for (int c = 0; c < C_; ++c) {
    const float* pl = sl + (size_t)b * CHW_ + (size_t)c * HW_;
    for (int e = tid; e < 18*18; e += 256) {
      int r = e / 18, cc = e - r * 18;
      int ci = min(max(i0 - 1 + r, 0), H_-1);
      int cj = min(max(j0 - 1 + cc, 0), W_-1);
      xs[c][r][cc] = pl[ci*W_ + cj];
    }
  }
  __syncthreads();
  bool mask = false;
  #pragma unroll
  for (int dr = 0; dr < 3; ++dr)
    #pragma unroll
    for (int dc = 0; dc < 3; ++dc)
      mask |= (kls[li+dr][lj+dc] > eps);
  int best = INF_, dir = 0;
  #pragma unroll
  for (int k = 0; k < 9; ++k) {
    int r = dss[li+1+nx[k]][lj+1+ny[k]];
    if (r < best) { best = r; dir = k; }
  }
  bool valid = mask && (dir != 8);
  float term = 0.f;
  if (valid) {
    int label = min(dir, 7);
    float lzc = lzs[li+1][lj+1];
    float xc[C_];
    #pragma unroll
    for (int c = 0; c < C_; ++c) xc[c] = xs[c][li+1][lj+1];
    float klmax = -1e30f, kll = 0.f, klb[8];
    #pragma unroll
    for (int k = 0; k < 8; ++k) {
      int rn = li + 1 + nx[k], cn = lj + 1 + ny[k];
      float lzn = lzs[rn][cn], Sn = Ss[rn][cn];
      float dot = 0.f;
      #pragma unroll
      for (int c = 0; c < C_; ++c) dot += expf(xs[c][rn][cn] - lzn) * xc[c];
      float kv = Sn - dot + lzc;
      klb[k] = kv;
      klmax = fmaxf(klmax, kv);
      if (k == label) kll = kv;
    }
    float sume = 0.f;
    #pragma unroll
    for (int k = 0; k < 8; ++k) sume += expf(klb[k] - klmax);
    float ce = klmax + logf(sume) - kll;
    float dv = (float)dss[li+1][lj+1];
    term = ce + fminf(dv, 20.f) * (1.f / 20.f);
  }
  block_reduce_add_256(term, out);
}

// ---------------- launch -----------------------------------------------------
extern "C" void kernel_launch(void* const* d_in, const int* in_sizes, int n_in,
                              void* d_out, int out_size, void* d_ws, size_t ws_size,
                              hipStream_t stream) {
  const float* sl  = (const float*)d_in[0];
  const int*   tgt = (const int*)d_in[1];
  float* out = (float*)d_out;

  float* logZ    = (float*)d_ws;
  float* S       = logZ + NPIX_;
  float* kl_map  = S + NPIX_;
  int*   dist    = (int*)(kl_map + NPIX_);
  int*   R       = dist + NPIX_;
  float* eps_tab = (float*)(R + NPIX_);
  int*   hist    = (int*)(eps_tab + NEPS_);
  float* eps_sel = (float*)(hist + 258);

  k_rowdt<<<B_*H_, W_, 0, stream>>>(tgt, R, eps_tab, hist, out);
  k_coldt<<<B_*W_, H_, 0, stream>>>(R, dist);
  k_stats<<<NPIX_/256, 256, 0, stream>>>(sl, tgt, logZ, S, out);
  k_klmap<<<NPIX_/256, 256, 0, stream>>>(sl, logZ, S, kl_map, eps_tab, hist);
  k_eps  <<<1, 256, 0, stream>>>(hist, eps_tab, eps_sel);
  dim3 gf(W_/16, H_/16, B_);
  k_final<<<gf, 256, 0, stream>>>(sl, dist, kl_map, logZ, S, eps_sel, out);
}

// Round 3
// 192.621 us; speedup vs baseline: 1.2562x; 1.2562x over previous
//
#include <hip/hip_runtime.h>
#include <math.h>

#define B_    4
#define C_    19
#define H_    320
#define W_    320
#define HW_   (H_*W_)
#define CHW_  (C_*HW_)
#define NPIX_ (B_*HW_)
#define NEPS_ 256
#define BIGI_ (1<<20)
#define INF_  0x3fffffff
#define IGN_  255

// ---------------- reduction helper (256-thread blocks = 4 waves) -------------
__device__ __forceinline__ void block_reduce_add_256(float v, float* out) {
  #pragma unroll
  for (int o = 32; o > 0; o >>= 1) v += __shfl_down(v, o);
  __shared__ float sh[4];
  int lane = threadIdx.x & 63, wid = threadIdx.x >> 6;
  if (lane == 0) sh[wid] = v;
  __syncthreads();
  if (threadIdx.x == 0) atomicAdd(out, sh[0] + sh[1] + sh[2] + sh[3]);
}

// ---------------- row-wise 1D seed distance (Hillis-Steele min scans) --------
// Block 0 additionally initializes eps table / hist / out / worklist counter.
__global__ __launch_bounds__(W_) void k_rowdt(const int* __restrict__ tgt, int* __restrict__ R,
                                              float* eps_tab, int* hist, float* out, int* counter) {
  int b = blockIdx.x / H_, i = blockIdx.x % H_, j = threadIdx.x;
  const int* t = tgt + b * HW_;
  int tij = t[i*W_ + j];
  bool bnd = (tij == IGN_);
  if (i < H_-1) bnd |= (t[(i+1)*W_ + j] != tij);
  if (j < W_-1) bnd |= (t[i*W_ + j + 1] != tij);
  int s = bnd ? 0 : BIGI_;
  __shared__ int a[W_], c[W_];
  a[j] = s - j; c[j] = s + j;
  for (int ofs = 1; ofs < W_; ofs <<= 1) {
    __syncthreads();
    int av = (j >= ofs)      ? a[j-ofs] : INF_;
    int cv = (j + ofs < W_)  ? c[j+ofs] : INF_;
    __syncthreads();
    a[j] = min(a[j], av); c[j] = min(c[j], cv);
  }
  int Rv = min(a[j] + j, c[j] - j);
  R[(b*H_ + i)*W_ + j] = Rv;
  if (blockIdx.x == 0) {
    if (j < 257) hist[j] = 0;
    if (j == 0) {
      float e = 1e-5f;
      for (int k = 0; k < NEPS_; ++k) { eps_tab[k] = e; e *= 1.2f; }
      out[0] = 0.f;
      counter[0] = 0;
    }
  }
}

// ---------------- column combine: dist = min_i max(|i-i0|, R_i) -------------
__global__ __launch_bounds__(H_) void k_coldt(const int* __restrict__ R, int* __restrict__ dist) {
  int b = blockIdx.x / W_, j = blockIdx.x % W_, tid = threadIdx.x;
  __shared__ int lev[9][H_];
  lev[0][tid] = R[(b*H_ + tid)*W_ + j];
  for (int l = 1; l <= 8; ++l) {
    int half = 1 << (l-1);
    __syncthreads();
    int other = (tid + half < H_) ? lev[l-1][tid + half] : INF_;
    lev[l][tid] = min(lev[l-1][tid], other);
  }
  __syncthreads();
  int i0 = tid;
  auto feas = [&](int dd) -> bool {
    int lo = max(0, i0 - dd), hi = min(H_-1, i0 + dd);
    int len = hi - lo + 1;
    int l = 31 - __clz(len);
    int m = min(lev[l][lo], lev[l][hi - (1 << l) + 1]);
    return m <= dd;
  };
  int d;
  if (!feas(512)) d = B_ + 1 + H_ + W_;          // 645: no seed in image
  else {
    int lo = 0, hi = 512;
    while (lo < hi) { int mid = (lo + hi) >> 1; if (feas(mid)) hi = mid; else lo = mid + 1; }
    d = lo;
  }
  dist[(b*H_ + i0)*W_ + j] = d;
}

// ---------------- per-pixel softmax stats + target loss ---------------------
__global__ __launch_bounds__(256) void k_stats(const float* __restrict__ sl, const int* __restrict__ tgt,
                                               float* __restrict__ logZ, float* __restrict__ S,
                                               float* __restrict__ out) {
  int idx = blockIdx.x * 256 + threadIdx.x;
  int b = idx / HW_; int pix = idx - b * HW_;
  const float* base = sl + (size_t)b * CHW_ + pix;
  float x[C_]; float m = -1e30f;
  #pragma unroll
  for (int c = 0; c < C_; ++c) { x[c] = base[c*HW_]; m = fmaxf(m, x[c]); }
  float se = 0.f, E = 0.f;
  #pragma unroll
  for (int c = 0; c < C_; ++c) { float e = expf(x[c] - m); se += e; E += e * x[c]; }
  float lz = m + logf(se);
  logZ[idx] = lz;
  S[idx] = E / se - lz;
  int t = tgt[idx];
  float nll = (t != IGN_) ? (lz - base[t*HW_]) : 0.f;
  block_reduce_add_256(nll, out);
}

// ---------------- kl_map (tb+lr KL) + histogram over eps table --------------
__global__ __launch_bounds__(256) void k_klmap(const float* __restrict__ sl, const float* __restrict__ logZ,
                                               const float* __restrict__ S, float* __restrict__ kl_map,
                                               const float* __restrict__ eps_tab, int* __restrict__ hist) {
  __shared__ int sh[257];
  __shared__ float et[NEPS_];
  for (int e = threadIdx.x; e < 257; e += 256) sh[e] = 0;
  for (int e = threadIdx.x; e < NEPS_; e += 256) et[e] = eps_tab[e];
  __syncthreads();
  int idx = blockIdx.x * 256 + threadIdx.x;
  int b = idx / HW_; int pix = idx - b * HW_;
  int i = pix / W_, j = pix - i * W_;
  const float* base = sl + (size_t)b * CHW_ + pix;
  float lz = logZ[idx], Sv = S[idx];
  float p[C_];
  #pragma unroll
  for (int c = 0; c < C_; ++c) p[c] = expf(base[c*HW_] - lz);
  float kl = 0.f;
  if (i < H_-1) {
    const float* bd = base + W_;
    float dot = 0.f;
    #pragma unroll
    for (int c = 0; c < C_; ++c) dot += p[c] * bd[c*HW_];
    kl += Sv - (dot - logZ[idx + W_]);
  }
  if (j < W_-1) {
    const float* br = base + 1;
    float dot = 0.f;
    #pragma unroll
    for (int c = 0; c < C_; ++c) dot += p[c] * br[c*HW_];
    kl += Sv - (dot - logZ[idx + 1]);
  }
  kl_map[idx] = kl;
  // g = #{k : e_k < kl}  (lower_bound; identical float compare as reference)
  int lo = 0, hi = NEPS_;
  while (lo < hi) { int mid = (lo + hi) >> 1; if (et[mid] < kl) lo = mid + 1; else hi = mid; }
  atomicAdd(&sh[lo], 1);
  __syncthreads();
  for (int e = threadIdx.x; e < 257; e += 256)
    if (sh[e]) atomicAdd(&hist[e], sh[e]);
}

// ---------------- eps selection: first k with count(>e_k) <= 5120 -----------
__global__ __launch_bounds__(256) void k_eps(const int* __restrict__ hist, const float* __restrict__ eps_tab,
                                             float* __restrict__ eps_sel) {
  __shared__ int h[257];
  __shared__ int bestk;
  int t = threadIdx.x;
  h[t] = hist[t];
  if (t == 0) { h[256] = hist[256]; bestk = NEPS_ - 1; }
  __syncthreads();
  int cnt = 0;
  for (int m = t + 1; m <= 256; ++m) cnt += h[m];
  if (cnt <= 5120) atomicMin(&bestk, t);
  __syncthreads();
  if (t == 0) eps_sel[0] = eps_tab[bestk];
}

// ---------------- mask+direction (dense, cheap) + worklist compaction -------
// Also accumulates the min(dist,20)/20 term (needs no logits).
__global__ __launch_bounds__(256) void k_mask(const float* __restrict__ kl_map, const int* __restrict__ dist,
                                              const float* __restrict__ eps_sel, int* __restrict__ worklist,
                                              int* __restrict__ counter, float* __restrict__ out) {
  const int nx[9] = {1,-1,0,0,-1,1,-1,1,0};
  const int ny[9] = {0,0,-1,1,1,1,-1,-1,0};
  int idx = blockIdx.x * 256 + threadIdx.x;
  int b = idx / HW_; int pix = idx - b * HW_;
  int i = pix / W_, j = pix - i * W_;
  float eps = eps_sel[0];
  const float* klb = kl_map + b * HW_;
  const int*   db  = dist   + b * HW_;
  bool mask = false;
  #pragma unroll
  for (int dr = -1; dr <= 1; ++dr)
    #pragma unroll
    for (int dc = -1; dc <= 1; ++dc) {
      int ii = i + dr, jj = j + dc;
      if (ii >= 0 && ii < H_ && jj >= 0 && jj < W_)
        mask |= (klb[ii*W_ + jj] > eps);
    }
  int best = INF_, dir = 0;
  #pragma unroll
  for (int k = 0; k < 9; ++k) {
    int ii = i + nx[k], jj = j + ny[k];
    int r = (ii >= 0 && ii < H_ && jj >= 0 && jj < W_) ? db[ii*W_ + jj] : 100000;
    if (r < best) { best = r; dir = k; }
  }
  bool valid = mask && (dir != 8);
  float dterm = valid ? fminf((float)db[i*W_ + j], 20.f) * (1.f/20.f) : 0.f;
  // ballot compaction (order: block-scrambled, lane-contiguous runs preserved)
  __shared__ int wcnt[4];
  __shared__ int bbase;
  int lane = threadIdx.x & 63, wid = threadIdx.x >> 6;
  unsigned long long vote = __ballot(valid);
  if (lane == 0) wcnt[wid] = __popcll(vote);
  __syncthreads();
  if (threadIdx.x == 0) {
    int c0 = wcnt[0], c1 = wcnt[1], c2 = wcnt[2], c3 = wcnt[3];
    int tot = c0 + c1 + c2 + c3;
    bbase = tot ? atomicAdd(counter, tot) : 0;
    wcnt[0] = 0; wcnt[1] = c0; wcnt[2] = c0 + c1; wcnt[3] = c0 + c1 + c2;
  }
  __syncthreads();
  if (valid) {
    int pos = bbase + wcnt[wid] + __popcll(vote & ((1ULL << lane) - 1ULL));
    worklist[pos] = idx | (min(dir, 7) << 24);
  }
  block_reduce_add_256(dterm, out);
}

// ---------------- sparse CE over worklist (all lanes active) ----------------
__global__ __launch_bounds__(256) void k_ce(const float* __restrict__ sl, const float* __restrict__ logZ,
                                            const float* __restrict__ S, const int* __restrict__ worklist,
                                            const int* __restrict__ counter, float* __restrict__ out) {
  const int nx[8] = {1,-1,0,0,-1,1,-1,1};
  const int ny[8] = {0,0,-1,1,1,1,-1,-1};
  int count = counter[0];
  float acc = 0.f;
  for (int w = blockIdx.x * 256 + threadIdx.x; w < count; w += gridDim.x * 256) {
    int word = worklist[w];
    int idx = word & 0xFFFFFF, label = word >> 24;
    int b = idx / HW_; int pix = idx - b * HW_;
    int i = pix / W_, j = pix - i * W_;
    const float* base = sl + (size_t)b * CHW_;
    float lzc = logZ[idx];
    float xc[C_];
    #pragma unroll
    for (int c = 0; c < C_; ++c) xc[c] = base[c*HW_ + pix];
    float klmax = -1e30f, kll = 0.f, klb[8];
    #pragma unroll
    for (int k = 0; k < 8; ++k) {
      int ic = min(max(i + nx[k], 0), H_-1);
      int jc = min(max(j + ny[k], 0), W_-1);
      int npx = ic*W_ + jc;
      int nidx = b*HW_ + npx;
      float lzn = logZ[nidx], Sn = S[nidx];
      float dot = 0.f;
      #pragma unroll
      for (int c = 0; c < C_; ++c) dot += expf(base[c*HW_ + npx] - lzn) * xc[c];
      float kv = Sn - dot + lzc;
      klb[k] = kv;
      klmax = fmaxf(klmax, kv);
      if (k == label) kll = kv;
    }
    float sume = 0.f;
    #pragma unroll
    for (int k = 0; k < 8; ++k) sume += expf(klb[k] - klmax);
    acc += klmax + logf(sume) - kll;
  }
  block_reduce_add_256(acc, out);
}

// ---------------- launch -----------------------------------------------------
extern "C" void kernel_launch(void* const* d_in, const int* in_sizes, int n_in,
                              void* d_out, int out_size, void* d_ws, size_t ws_size,
                              hipStream_t stream) {
  const float* sl  = (const float*)d_in[0];
  const int*   tgt = (const int*)d_in[1];
  float* out = (float*)d_out;

  float* logZ    = (float*)d_ws;
  float* S       = logZ + NPIX_;
  float* kl_map  = S + NPIX_;
  int*   dist    = (int*)(kl_map + NPIX_);
  int*   R       = dist + NPIX_;          // dead after k_coldt; reused as worklist
  float* eps_tab = (float*)(R + NPIX_);
  int*   hist    = (int*)(eps_tab + NEPS_);
  float* eps_sel = (float*)(hist + 258);
  int*   counter = (int*)(eps_sel + 1);
  int*   worklist = R;

  k_rowdt<<<B_*H_, W_, 0, stream>>>(tgt, R, eps_tab, hist, out, counter);
  k_coldt<<<B_*W_, H_, 0, stream>>>(R, dist);
  k_stats<<<NPIX_/256, 256, 0, stream>>>(sl, tgt, logZ, S, out);
  k_klmap<<<NPIX_/256, 256, 0, stream>>>(sl, logZ, S, kl_map, eps_tab, hist);
  k_eps  <<<1, 256, 0, stream>>>(hist, eps_tab, eps_sel);
  k_mask <<<NPIX_/256, 256, 0, stream>>>(kl_map, dist, eps_sel, worklist, counter, out);
  k_ce   <<<512, 256, 0, stream>>>(sl, logZ, S, worklist, counter, out);
}

// Round 4
// 157.123 us; speedup vs baseline: 1.5401x; 1.2259x over previous
//
#include <hip/hip_runtime.h>
#include <math.h>

#define B_    4
#define C_    19
#define H_    320
#define W_    320
#define HW_   (H_*W_)
#define CHW_  (C_*HW_)
#define NPIX_ (B_*HW_)
#define NEPS_ 256
#define BIGI_ (1<<20)
#define INF_  0x3fffffff
#define IGN_  255

// ---------------- reduction helper (256-thread blocks = 4 waves) -------------
__device__ __forceinline__ void block_reduce_add_256(float v, float* out) {
  #pragma unroll
  for (int o = 32; o > 0; o >>= 1) v += __shfl_down(v, o);
  __shared__ float sh[4];
  int lane = threadIdx.x & 63, wid = threadIdx.x >> 6;
  if (lane == 0) sh[wid] = v;
  __syncthreads();
  if (threadIdx.x == 0) atomicAdd(out, sh[0] + sh[1] + sh[2] + sh[3]);
}

// ---------------- row-wise 1D seed distance (Hillis-Steele min scans) --------
// Block 0 additionally initializes eps table / hist / out / worklist counter.
__global__ __launch_bounds__(W_) void k_rowdt(const int* __restrict__ tgt, int* __restrict__ R,
                                              float* eps_tab, int* hist, float* out, int* counter) {
  int b = blockIdx.x / H_, i = blockIdx.x % H_, j = threadIdx.x;
  const int* t = tgt + b * HW_;
  int tij = t[i*W_ + j];
  bool bnd = (tij == IGN_);
  if (i < H_-1) bnd |= (t[(i+1)*W_ + j] != tij);
  if (j < W_-1) bnd |= (t[i*W_ + j + 1] != tij);
  int s = bnd ? 0 : BIGI_;
  __shared__ int a[W_], c[W_];
  a[j] = s - j; c[j] = s + j;
  for (int ofs = 1; ofs < W_; ofs <<= 1) {
    __syncthreads();
    int av = (j >= ofs)      ? a[j-ofs] : INF_;
    int cv = (j + ofs < W_)  ? c[j+ofs] : INF_;
    __syncthreads();
    a[j] = min(a[j], av); c[j] = min(c[j], cv);
  }
  int Rv = min(a[j] + j, c[j] - j);
  R[(b*H_ + i)*W_ + j] = Rv;
  if (blockIdx.x == 0) {
    if (j < 257) hist[j] = 0;
    if (j == 0) {
      float e = 1e-5f;
      for (int k = 0; k < NEPS_; ++k) { eps_tab[k] = e; e *= 1.2f; }
      out[0] = 0.f;
      counter[0] = 0;
    }
  }
}

// ---------------- column combine: dist = min_i max(|i-i0|, R_i) -------------
__global__ __launch_bounds__(H_) void k_coldt(const int* __restrict__ R, int* __restrict__ dist) {
  int b = blockIdx.x / W_, j = blockIdx.x % W_, tid = threadIdx.x;
  __shared__ int lev[9][H_];
  lev[0][tid] = R[(b*H_ + tid)*W_ + j];
  for (int l = 1; l <= 8; ++l) {
    int half = 1 << (l-1);
    __syncthreads();
    int other = (tid + half < H_) ? lev[l-1][tid + half] : INF_;
    lev[l][tid] = min(lev[l-1][tid], other);
  }
  __syncthreads();
  int i0 = tid;
  auto feas = [&](int dd) -> bool {
    int lo = max(0, i0 - dd), hi = min(H_-1, i0 + dd);
    int len = hi - lo + 1;
    int l = 31 - __clz(len);
    int m = min(lev[l][lo], lev[l][hi - (1 << l) + 1]);
    return m <= dd;
  };
  int d;
  if (!feas(512)) d = B_ + 1 + H_ + W_;          // 645: no seed in image
  else {
    int lo = 0, hi = 512;
    while (lo < hi) { int mid = (lo + hi) >> 1; if (feas(mid)) hi = mid; else lo = mid + 1; }
    d = lo;
  }
  dist[(b*H_ + i0)*W_ + j] = d;
}

// ---------------- fused softmax stats + target nll + kl_map + histogram -----
// One pass over slices: self softmax from registers; down/right neighbor logZ
// recomputed by streaming their channels twice (2nd pass hits L1).
__global__ __launch_bounds__(256) void k_fused(const float* __restrict__ sl, const int* __restrict__ tgt,
                                               float* __restrict__ logZ, float* __restrict__ S,
                                               float* __restrict__ kl_map, const float* __restrict__ eps_tab,
                                               int* __restrict__ hist, float* __restrict__ out) {
  __shared__ int sh[257];
  __shared__ float et[NEPS_];
  for (int e = threadIdx.x; e < 257; e += 256) sh[e] = 0;
  for (int e = threadIdx.x; e < NEPS_; e += 256) et[e] = eps_tab[e];
  __syncthreads();
  int idx = blockIdx.x * 256 + threadIdx.x;
  int b = idx / HW_; int pix = idx - b * HW_;
  int i = pix / W_, j = pix - i * W_;
  const float* base = sl + (size_t)b * CHW_ + pix;
  float x[C_]; float m = -1e30f;
  #pragma unroll
  for (int c = 0; c < C_; ++c) { x[c] = base[c*HW_]; m = fmaxf(m, x[c]); }
  float se = 0.f, E = 0.f;
  #pragma unroll
  for (int c = 0; c < C_; ++c) { float e = expf(x[c] - m); se += e; E += e * x[c]; }
  float lz = m + logf(se);
  float Sv = E / se - lz;
  logZ[idx] = lz; S[idx] = Sv;
  int t = tgt[idx];
  float nll = (t != IGN_) ? (lz - base[t*HW_]) : 0.f;
  // convert x -> p in place
  #pragma unroll
  for (int c = 0; c < C_; ++c) x[c] = expf(x[c] - lz);
  float kl = 0.f;
  if (i < H_-1) {
    const float* bd = base + W_;
    float md = -1e30f;
    #pragma unroll
    for (int c = 0; c < C_; ++c) md = fmaxf(md, bd[c*HW_]);
    float sed = 0.f, dot = 0.f;
    #pragma unroll
    for (int c = 0; c < C_; ++c) { float y = bd[c*HW_]; sed += expf(y - md); dot += x[c] * y; }
    kl += Sv - (dot - (md + logf(sed)));
  }
  if (j < W_-1) {
    const float* br = base + 1;
    float mr = -1e30f;
    #pragma unroll
    for (int c = 0; c < C_; ++c) mr = fmaxf(mr, br[c*HW_]);
    float ser = 0.f, dot = 0.f;
    #pragma unroll
    for (int c = 0; c < C_; ++c) { float y = br[c*HW_]; ser += expf(y - mr); dot += x[c] * y; }
    kl += Sv - (dot - (mr + logf(ser)));
  }
  kl_map[idx] = kl;
  // bin = #{k : e_k < kl} (lower_bound; identical float compare as reference)
  int lo = 0, hi = NEPS_;
  while (lo < hi) { int mid = (lo + hi) >> 1; if (et[mid] < kl) lo = mid + 1; else hi = mid; }
  atomicAdd(&sh[lo], 1);
  __syncthreads();
  for (int e = threadIdx.x; e < 257; e += 256)
    if (sh[e]) atomicAdd(&hist[e], sh[e]);
  block_reduce_add_256(nll, out);
}

// ---------------- mask+direction + inline eps + worklist compaction ---------
// eps recomputed per block from hist via parallel suffix scan (~500 cyc).
__global__ __launch_bounds__(256) void k_mask(const float* __restrict__ kl_map, const int* __restrict__ dist,
                                              const int* __restrict__ hist, const float* __restrict__ eps_tab,
                                              int* __restrict__ worklist, int* __restrict__ counter,
                                              float* __restrict__ out) {
  const int nx[9] = {1,-1,0,0,-1,1,-1,1,0};
  const int ny[9] = {0,0,-1,1,1,1,-1,-1,0};
  int tid = threadIdx.x;
  __shared__ int g[256];
  __shared__ int bestk;
  g[tid] = hist[tid + 1];                 // bins 1..256
  if (tid == 0) bestk = NEPS_ - 1;
  __syncthreads();
  #pragma unroll
  for (int ofs = 1; ofs < 256; ofs <<= 1) {
    int v = g[tid] + ((tid + ofs < 256) ? g[tid + ofs] : 0);
    __syncthreads();
    g[tid] = v;
    __syncthreads();
  }
  // g[t] = #{kl > e_t}; first t with count <= pixel_ratio
  if (g[tid] <= 5120) atomicMin(&bestk, tid);
  __syncthreads();
  float eps = eps_tab[bestk];

  int idx = blockIdx.x * 256 + tid;
  int b = idx / HW_; int pix = idx - b * HW_;
  int i = pix / W_, j = pix - i * W_;
  const float* klb = kl_map + b * HW_;
  const int*   db  = dist   + b * HW_;
  bool mask = false;
  #pragma unroll
  for (int dr = -1; dr <= 1; ++dr)
    #pragma unroll
    for (int dc = -1; dc <= 1; ++dc) {
      int ii = i + dr, jj = j + dc;
      if (ii >= 0 && ii < H_ && jj >= 0 && jj < W_)
        mask |= (klb[ii*W_ + jj] > eps);
    }
  int best = INF_, dir = 0;
  #pragma unroll
  for (int k = 0; k < 9; ++k) {
    int ii = i + nx[k], jj = j + ny[k];
    int r = (ii >= 0 && ii < H_ && jj >= 0 && jj < W_) ? db[ii*W_ + jj] : 100000;
    if (r < best) { best = r; dir = k; }
  }
  bool valid = mask && (dir != 8);
  float dterm = valid ? fminf((float)db[i*W_ + j], 20.f) * (1.f/20.f) : 0.f;
  // ballot compaction
  __shared__ int wcnt[4];
  __shared__ int bbase;
  int lane = tid & 63, wid = tid >> 6;
  unsigned long long vote = __ballot(valid);
  if (lane == 0) wcnt[wid] = __popcll(vote);
  __syncthreads();
  if (tid == 0) {
    int c0 = wcnt[0], c1 = wcnt[1], c2 = wcnt[2], c3 = wcnt[3];
    int tot = c0 + c1 + c2 + c3;
    bbase = tot ? atomicAdd(counter, tot) : 0;
    wcnt[0] = 0; wcnt[1] = c0; wcnt[2] = c0 + c1; wcnt[3] = c0 + c1 + c2;
  }
  __syncthreads();
  if (valid) {
    int pos = bbase + wcnt[wid] + __popcll(vote & ((1ULL << lane) - 1ULL));
    worklist[pos] = idx | (min(dir, 7) << 24);
  }
  block_reduce_add_256(dterm, out);
}

// ---------------- sparse CE: 8 lanes per entry (lane k = neighbor k) --------
__global__ __launch_bounds__(256) void k_ce(const float* __restrict__ sl, const float* __restrict__ logZ,
                                            const float* __restrict__ S, const int* __restrict__ worklist,
                                            const int* __restrict__ counter, float* __restrict__ out) {
  const int nx[8] = {1,-1,0,0,-1,1,-1,1};
  const int ny[8] = {0,0,-1,1,1,1,-1,-1};
  int count = counter[0];
  int lane = threadIdx.x & 63;
  int k = lane & 7;
  int gid = (blockIdx.x * 256 + threadIdx.x) >> 3;
  int ngrp = (gridDim.x * 256) >> 3;
  int knx = nx[k], kny = ny[k];
  float acc = 0.f;
  for (int w = gid; w < count; w += ngrp) {
    int word = worklist[w];
    int idx = word & 0xFFFFFF, label = word >> 24;
    int b = idx / HW_; int pix = idx - b * HW_;
    int i = pix / W_, j = pix - i * W_;
    const float* base = sl + (size_t)b * CHW_;
    float lzc = logZ[idx];
    int ic = min(max(i + knx, 0), H_-1);
    int jc = min(max(j + kny, 0), W_-1);
    int npx = ic*W_ + jc;
    int nidx = b*HW_ + npx;
    float lzn = logZ[nidx], Sn = S[nidx];
    float dot = 0.f;
    #pragma unroll
    for (int c = 0; c < C_; ++c)
      dot += expf(base[c*HW_ + npx] - lzn) * base[c*HW_ + pix];
    float kv = Sn - dot + lzc;
    // 8-wide butterfly: max, then sum of exp
    float kmax = kv;
    #pragma unroll
    for (int o = 1; o < 8; o <<= 1) kmax = fmaxf(kmax, __shfl_xor(kmax, o));
    float s = expf(kv - kmax);
    #pragma unroll
    for (int o = 1; o < 8; o <<= 1) s += __shfl_xor(s, o);
    float kll = __shfl(kv, (lane & ~7) | label);
    if (k == 0) acc += kmax + logf(s) - kll;
  }
  block_reduce_add_256(acc, out);
}

// ---------------- launch -----------------------------------------------------
extern "C" void kernel_launch(void* const* d_in, const int* in_sizes, int n_in,
                              void* d_out, int out_size, void* d_ws, size_t ws_size,
                              hipStream_t stream) {
  const float* sl  = (const float*)d_in[0];
  const int*   tgt = (const int*)d_in[1];
  float* out = (float*)d_out;

  float* logZ    = (float*)d_ws;
  float* S       = logZ + NPIX_;
  float* kl_map  = S + NPIX_;
  int*   dist    = (int*)(kl_map + NPIX_);
  int*   R       = dist + NPIX_;          // dead after k_coldt; reused as worklist
  float* eps_tab = (float*)(R + NPIX_);
  int*   hist    = (int*)(eps_tab + NEPS_);
  float* eps_sel = (float*)(hist + 258);
  int*   counter = (int*)(eps_sel + 1);
  int*   worklist = R;

  k_rowdt<<<B_*H_, W_, 0, stream>>>(tgt, R, eps_tab, hist, out, counter);
  k_coldt<<<B_*W_, H_, 0, stream>>>(R, dist);
  k_fused<<<NPIX_/256, 256, 0, stream>>>(sl, tgt, logZ, S, kl_map, eps_tab, hist, out);
  k_mask <<<NPIX_/256, 256, 0, stream>>>(kl_map, dist, hist, eps_tab, worklist, counter, out);
  k_ce   <<<512, 256, 0, stream>>>(sl, logZ, S, worklist, counter, out);
}